// Round 1
// baseline (407.161 us; speedup 1.0000x reference)
//
#include <hip/hip_runtime.h>
#include <math.h>

#define B_   8
#define T_   96
#define N_   1024
#define C_   64
#define H_   64
#define BT_  768
#define EMB_ 8

// ---------------------------------------------------------------------------
// k_wp: wp1[d][c] = sum_i w_in[i]*wpool[d][i][c];  wpb same with b_in.  (1 block)
// ---------------------------------------------------------------------------
__global__ __launch_bounds__(256) void k_wp(const float* __restrict__ wpool,
                                            const float* __restrict__ w_in,
                                            const float* __restrict__ b_in,
                                            float* __restrict__ wp1,
                                            float* __restrict__ wpb) {
    for (int e = threadIdx.x; e < EMB_ * C_; e += 256) {
        int d = e >> 6, c = e & 63;
        float s1 = 0.f, s2 = 0.f;
        for (int i = 0; i < C_; ++i) {
            float w = wpool[(d * C_ + i) * C_ + c];
            s1 += w_in[i] * w;
            s2 += b_in[i] * w;
        }
        wp1[e] = s1;
        wpb[e] = s2;
    }
}

// ---------------------------------------------------------------------------
// k_w1n: W1n[n][c] = sum_d emb[type[n]][d]*wp1[d][c];  B1n same with wpb.
// grid 256 x 256 threads = 65536
// ---------------------------------------------------------------------------
__global__ __launch_bounds__(256) void k_w1n(const float* __restrict__ wp1,
                                             const float* __restrict__ wpb,
                                             const float* __restrict__ emb,
                                             const int* __restrict__ ntype,
                                             float* __restrict__ W1n,
                                             float* __restrict__ B1n) {
    int e = blockIdx.x * 256 + threadIdx.x;  // < 65536
    int n = e >> 6, c = e & 63;
    int ty = ntype[n];
    float s1 = 0.f, s2 = 0.f;
#pragma unroll
    for (int d = 0; d < EMB_; ++d) {
        float ev = emb[ty * EMB_ + d];
        s1 += ev * wp1[d * C_ + c];
        s2 += ev * wpb[d * C_ + c];
    }
    W1n[e] = s1;
    B1n[e] = s2;
}

// ---------------------------------------------------------------------------
// k_rs: rs[n] = sum_m adj[n][m].   grid = 1024 blocks
// ---------------------------------------------------------------------------
__global__ __launch_bounds__(256) void k_rs(const float* __restrict__ adj,
                                            float* __restrict__ rs) {
    int row = blockIdx.x;
    float s = 0.f;
    for (int m = threadIdx.x; m < N_; m += 256) s += adj[row * N_ + m];
#pragma unroll
    for (int off = 32; off; off >>= 1) s += __shfl_down(s, off);
    __shared__ float red[4];
    if ((threadIdx.x & 63) == 0) red[threadIdx.x >> 6] = s;
    __syncthreads();
    if (threadIdx.x == 0) rs[row] = red[0] + red[1] + red[2] + red[3];
}

// ---------------------------------------------------------------------------
// k_ax: ax[bt][n] = sum_m x[bt][m] * adj[n][m]   (NT SGEMM, M=768 N=1024 K=1024)
// 64x64 tiles, 256 threads, 4x4 per thread, K-chunk 32, LDS transposed stage.
// ---------------------------------------------------------------------------
__global__ __launch_bounds__(256) void k_ax(const float* __restrict__ x,
                                            const float* __restrict__ adj,
                                            float* __restrict__ ax) {
    __shared__ float As[32][68];
    __shared__ float Bs[32][68];
    int bx = blockIdx.x;  // n tile (16)
    int by = blockIdx.y;  // bt tile (12)
    int tid = threadIdx.x;
    int tx = tid & 15, ty = tid >> 4;
    int r = tid >> 2;             // 0..63 staging row
    int kofs = (tid & 3) * 8;     // 0,8,16,24
    const float* xrow = x + (by * 64 + r) * N_;
    const float* arow = adj + (bx * 64 + r) * N_;
    float acc[4][4];
#pragma unroll
    for (int i = 0; i < 4; ++i)
#pragma unroll
        for (int j = 0; j < 4; ++j) acc[i][j] = 0.f;

    for (int k0 = 0; k0 < N_; k0 += 32) {
        float4 a0 = *(const float4*)(xrow + k0 + kofs);
        float4 a1 = *(const float4*)(xrow + k0 + kofs + 4);
        float4 b0 = *(const float4*)(arow + k0 + kofs);
        float4 b1 = *(const float4*)(arow + k0 + kofs + 4);
        __syncthreads();
        As[kofs + 0][r] = a0.x; As[kofs + 1][r] = a0.y;
        As[kofs + 2][r] = a0.z; As[kofs + 3][r] = a0.w;
        As[kofs + 4][r] = a1.x; As[kofs + 5][r] = a1.y;
        As[kofs + 6][r] = a1.z; As[kofs + 7][r] = a1.w;
        Bs[kofs + 0][r] = b0.x; Bs[kofs + 1][r] = b0.y;
        Bs[kofs + 2][r] = b0.z; Bs[kofs + 3][r] = b0.w;
        Bs[kofs + 4][r] = b1.x; Bs[kofs + 5][r] = b1.y;
        Bs[kofs + 6][r] = b1.z; Bs[kofs + 7][r] = b1.w;
        __syncthreads();
#pragma unroll
        for (int kk = 0; kk < 32; ++kk) {
            float4 av = *(const float4*)&As[kk][ty * 4];
            float4 bv = *(const float4*)&Bs[kk][tx * 4];
            float a[4] = {av.x, av.y, av.z, av.w};
            float b[4] = {bv.x, bv.y, bv.z, bv.w};
#pragma unroll
            for (int i = 0; i < 4; ++i)
#pragma unroll
                for (int j = 0; j < 4; ++j) acc[i][j] += a[i] * b[j];
        }
    }
    int obase = (by * 64 + ty * 4) * N_ + bx * 64 + tx * 4;
#pragma unroll
    for (int i = 0; i < 4; ++i) {
        float4 v = make_float4(acc[i][0], acc[i][1], acc[i][2], acc[i][3]);
        *(float4*)(ax + obase + i * N_) = v;
    }
}

// ---------------------------------------------------------------------------
// k_gn: per (bt, group) mean & rsqrt(var+eps) of
//   h[bt,c,n] = ax*W1n + rs*B1n + x*w_in + b_in  over (c in group, n).
// grid = 768 blocks
// ---------------------------------------------------------------------------
__global__ __launch_bounds__(256) void k_gn(const float* __restrict__ x,
                                            const float* __restrict__ ax,
                                            const float* __restrict__ W1n,
                                            const float* __restrict__ B1n,
                                            const float* __restrict__ rs,
                                            const float* __restrict__ w_in,
                                            const float* __restrict__ b_in,
                                            float* __restrict__ mu,
                                            float* __restrict__ rsig) {
    int bt = blockIdx.x;
    int tid = threadIdx.x;
    __shared__ float winv[64], binv[64];
    if (tid < 64) { winv[tid] = w_in[tid]; binv[tid] = b_in[tid]; }
    __syncthreads();
    float s[4] = {0.f, 0.f, 0.f, 0.f};
    float q[4] = {0.f, 0.f, 0.f, 0.f};
    for (int n = tid; n < N_; n += 256) {
        float axn = ax[bt * N_ + n];
        float xn = x[bt * N_ + n];
        float rsn = rs[n];
        const float4* pW = (const float4*)(W1n + n * 64);
        const float4* pB = (const float4*)(B1n + n * 64);
#pragma unroll
        for (int cc = 0; cc < 16; ++cc) {
            float4 wv = pW[cc];
            float4 bv = pB[cc];
            int g = cc >> 2;
            int c0 = cc * 4;
            float v0 = axn * wv.x + rsn * bv.x + xn * winv[c0 + 0] + binv[c0 + 0];
            float v1 = axn * wv.y + rsn * bv.y + xn * winv[c0 + 1] + binv[c0 + 1];
            float v2 = axn * wv.z + rsn * bv.z + xn * winv[c0 + 2] + binv[c0 + 2];
            float v3 = axn * wv.w + rsn * bv.w + xn * winv[c0 + 3] + binv[c0 + 3];
            s[g] += v0 + v1 + v2 + v3;
            q[g] += v0 * v0 + v1 * v1 + v2 * v2 + v3 * v3;
        }
    }
#pragma unroll
    for (int g = 0; g < 4; ++g) {
#pragma unroll
        for (int off = 32; off; off >>= 1) {
            s[g] += __shfl_down(s[g], off);
            q[g] += __shfl_down(q[g], off);
        }
    }
    __shared__ float redS[4][4], redQ[4][4];
    int w = tid >> 6, lane = tid & 63;
    if (lane == 0) {
#pragma unroll
        for (int g = 0; g < 4; ++g) { redS[w][g] = s[g]; redQ[w][g] = q[g]; }
    }
    __syncthreads();
    if (tid < 4) {
        float S = 0.f, Q = 0.f;
#pragma unroll
        for (int ww = 0; ww < 4; ++ww) { S += redS[ww][tid]; Q += redQ[ww][tid]; }
        const float inv = 1.f / 16384.f;
        float m = S * inv;
        float v = Q * inv - m * m;
        mu[bt * 4 + tid] = m;
        rsig[bt * 4 + tid] = rsqrtf(v + 1e-5f);
    }
}

// ---------------------------------------------------------------------------
// k_main: per (b, n): GN-apply -> temporal MLP -> residual -> SiLU -> out proj
// grid = (1024, 8), 256 threads.
// ---------------------------------------------------------------------------
__global__ __launch_bounds__(256) void k_main(const float* __restrict__ x,
                                              const float* __restrict__ ax,
                                              const float* __restrict__ W1n,
                                              const float* __restrict__ B1n,
                                              const float* __restrict__ rs,
                                              const float* __restrict__ mu,
                                              const float* __restrict__ rsig,
                                              const float* __restrict__ w_in,
                                              const float* __restrict__ b_in,
                                              const float* __restrict__ gn_w,
                                              const float* __restrict__ gn_b,
                                              const float* __restrict__ w1,
                                              const float* __restrict__ b1,
                                              const float* __restrict__ w2,
                                              const float* __restrict__ b2,
                                              const float* __restrict__ w_out,
                                              const float* __restrict__ b_out,
                                              float* __restrict__ out) {
    __shared__ float HtT[96][64];   // [t][c]  post-GN
    __shared__ float tmpT[64][64];  // [h][c]  relu hidden
    __shared__ float axv[96], xv[96];
    int n = blockIdx.x, b = blockIdx.y;
    int tid = threadIdx.x;

    if (tid < 96) {
        int bt = b * T_ + tid;
        axv[tid] = ax[bt * N_ + n];
        xv[tid] = x[bt * N_ + n];
    }
    __syncthreads();

    // phase 1: HtT[t][c] = GN(h)
    {
        int c = tid & 63;
        int t0 = tid >> 6;  // 0..3
        float wlc = W1n[n * 64 + c];
        float blc = B1n[n * 64 + c];
        float rsn = rs[n];
        float wic = w_in[c], bic = b_in[c];
        float gwc = gn_w[c], gbc = gn_b[c];
        int g = c >> 4;
#pragma unroll
        for (int i = 0; i < 24; ++i) {
            int t = t0 + 4 * i;
            int bt = b * T_ + t;
            float hv = axv[t] * wlc + rsn * blc + xv[t] * wic + bic;
            float m = mu[bt * 4 + g];
            float rg = rsig[bt * 4 + g];
            HtT[t][c] = (hv - m) * rg * gwc + gbc;
        }
    }
    __syncthreads();

    // phase 2: tmpT[h][c] = relu(b1[h] + sum_t HtT[t][c]*w1[h][t])
    {
        int q = tid & 15, rr = tid >> 4;
        int c0 = q * 4, h0 = rr * 4;
        float acc[4][4];
#pragma unroll
        for (int j = 0; j < 4; ++j) {
            float bj = b1[h0 + j];
            acc[0][j] = bj; acc[1][j] = bj; acc[2][j] = bj; acc[3][j] = bj;
        }
#pragma unroll 4
        for (int t = 0; t < 96; ++t) {
            float4 av = *(const float4*)&HtT[t][c0];
            float a[4] = {av.x, av.y, av.z, av.w};
            float wv0 = w1[(h0 + 0) * T_ + t];
            float wv1 = w1[(h0 + 1) * T_ + t];
            float wv2 = w1[(h0 + 2) * T_ + t];
            float wv3 = w1[(h0 + 3) * T_ + t];
#pragma unroll
            for (int i = 0; i < 4; ++i) {
                acc[i][0] += a[i] * wv0;
                acc[i][1] += a[i] * wv1;
                acc[i][2] += a[i] * wv2;
                acc[i][3] += a[i] * wv3;
            }
        }
#pragma unroll
        for (int i = 0; i < 4; ++i)
#pragma unroll
            for (int j = 0; j < 4; ++j)
                tmpT[h0 + j][c0 + i] = fmaxf(acc[i][j], 0.f);
    }
    __syncthreads();

    // phase 3: t_out[c][t] = b2[t] + sum_h tmpT[h][c]*w2[t][h]; then epilogue
    {
        int q = tid & 15, rr = tid >> 4;
        int c0 = q * 4, t0 = rr * 6;
        float acc2[4][6];
#pragma unroll
        for (int jt = 0; jt < 6; ++jt) {
            float bj = b2[t0 + jt];
            acc2[0][jt] = bj; acc2[1][jt] = bj; acc2[2][jt] = bj; acc2[3][jt] = bj;
        }
#pragma unroll 2
        for (int h = 0; h < 64; ++h) {
            float4 av = *(const float4*)&tmpT[h][c0];
            float a[4] = {av.x, av.y, av.z, av.w};
            float wv[6];
#pragma unroll
            for (int jt = 0; jt < 6; ++jt) wv[jt] = w2[(t0 + jt) * H_ + h];
#pragma unroll
            for (int i = 0; i < 4; ++i)
#pragma unroll
                for (int jt = 0; jt < 6; ++jt) acc2[i][jt] += a[i] * wv[jt];
        }
        float wo[4];
#pragma unroll
        for (int i = 0; i < 4; ++i) wo[i] = w_out[c0 + i];
        float bo = b_out[0];
#pragma unroll
        for (int jt = 0; jt < 6; ++jt) {
            int t = t0 + jt;
            float4 hv = *(const float4*)&HtT[t][c0];
            float hh[4] = {hv.x, hv.y, hv.z, hv.w};
            float p = 0.f;
#pragma unroll
            for (int i = 0; i < 4; ++i) {
                float z = hh[i] + acc2[i][jt];
                p += wo[i] * (z / (1.f + __expf(-z)));
            }
            p += __shfl_xor(p, 1);
            p += __shfl_xor(p, 2);
            p += __shfl_xor(p, 4);
            p += __shfl_xor(p, 8);
            if (q == 0) out[(b * T_ + t) * N_ + n] = p + bo;
        }
    }
}

// ---------------------------------------------------------------------------
extern "C" void kernel_launch(void* const* d_in, const int* in_sizes, int n_in,
                              void* d_out, int out_size, void* d_ws, size_t ws_size,
                              hipStream_t stream) {
    const float* x     = (const float*)d_in[0];
    const float* adj   = (const float*)d_in[1];
    const int*   ntype = (const int*)d_in[2];
    const float* w_in  = (const float*)d_in[3];
    const float* b_in  = (const float*)d_in[4];
    const float* wpool = (const float*)d_in[5];
    const float* emb   = (const float*)d_in[6];
    const float* gn_w  = (const float*)d_in[7];
    const float* gn_b  = (const float*)d_in[8];
    const float* w1    = (const float*)d_in[9];
    const float* b1    = (const float*)d_in[10];
    const float* w2    = (const float*)d_in[11];
    const float* b2    = (const float*)d_in[12];
    const float* w_out = (const float*)d_in[13];
    const float* b_out = (const float*)d_in[14];
    float* out = (float*)d_out;
    float* ws = (float*)d_ws;

    float* wp1 = ws;            // 512
    float* wpb = ws + 512;      // 512
    float* rsv = ws + 1024;     // 1024
    float* W1n = ws + 2048;     // 65536
    float* B1n = ws + 67584;    // 65536
    float* axb = ws + 133120;   // 786432
    float* muv = ws + 919552;   // 3072
    float* rgv = ws + 922624;   // 3072  (total 925696 floats = 3.70 MB)

    k_wp<<<dim3(1), dim3(256), 0, stream>>>(wpool, w_in, b_in, wp1, wpb);
    k_w1n<<<dim3(256), dim3(256), 0, stream>>>(wp1, wpb, emb, ntype, W1n, B1n);
    k_rs<<<dim3(1024), dim3(256), 0, stream>>>(adj, rsv);
    k_ax<<<dim3(16, 12), dim3(256), 0, stream>>>(x, adj, axb);
    k_gn<<<dim3(768), dim3(256), 0, stream>>>(x, axb, W1n, B1n, rsv, w_in, b_in, muv, rgv);
    k_main<<<dim3(1024, 8), dim3(256), 0, stream>>>(x, axb, W1n, B1n, rsv, muv, rgv,
                                                    w_in, b_in, gn_w, gn_b,
                                                    w1, b1, w2, b2, w_out, b_out, out);
}

// Round 3
// 210.072 us; speedup vs baseline: 1.9382x; 1.9382x over previous
//
#include <hip/hip_runtime.h>
#include <math.h>

#define B_   8
#define T_   96
#define N_   1024
#define C_   64
#define H_   64
#define BT_  768
#define EMB_ 8

typedef __attribute__((ext_vector_type(8))) short short8v;
typedef __attribute__((ext_vector_type(4))) float f32x4;

__device__ __forceinline__ ushort f2bf(float f) {
    unsigned int u = __float_as_uint(f);
    unsigned int r = (u + 0x7fffu + ((u >> 16) & 1u)) >> 16;
    return (ushort)r;
}
__device__ __forceinline__ float bf2f(ushort h) {
    return __uint_as_float(((unsigned int)h) << 16);
}

// ---------------------------------------------------------------------------
// k_wp: wp1[d][c] = sum_i w_in[i]*wpool[d][i][c];  wpb same with b_in.  (1 block)
// ---------------------------------------------------------------------------
__global__ __launch_bounds__(256) void k_wp(const float* __restrict__ wpool,
                                            const float* __restrict__ w_in,
                                            const float* __restrict__ b_in,
                                            float* __restrict__ wp1,
                                            float* __restrict__ wpb) {
    for (int e = threadIdx.x; e < EMB_ * C_; e += 256) {
        int d = e >> 6, c = e & 63;
        float s1 = 0.f, s2 = 0.f;
        for (int i = 0; i < C_; ++i) {
            float w = wpool[(d * C_ + i) * C_ + c];
            s1 += w_in[i] * w;
            s2 += b_in[i] * w;
        }
        wp1[e] = s1;
        wpb[e] = s2;
    }
}

// ---------------------------------------------------------------------------
// k_w1n: W1n[n][c] = sum_d emb[type[n]][d]*wp1[d][c];  B1n same with wpb.
// ---------------------------------------------------------------------------
__global__ __launch_bounds__(256) void k_w1n(const float* __restrict__ wp1,
                                             const float* __restrict__ wpb,
                                             const float* __restrict__ emb,
                                             const int* __restrict__ ntype,
                                             float* __restrict__ W1n,
                                             float* __restrict__ B1n) {
    int e = blockIdx.x * 256 + threadIdx.x;  // < 65536
    int n = e >> 6;
    int ty = ntype[n];
    float s1 = 0.f, s2 = 0.f;
#pragma unroll
    for (int d = 0; d < EMB_; ++d) {
        float ev = emb[ty * EMB_ + d];
        s1 += ev * wp1[d * C_ + (e & 63)];
        s2 += ev * wpb[d * C_ + (e & 63)];
    }
    W1n[e] = s1;
    B1n[e] = s2;
}

// ---------------------------------------------------------------------------
// k_rs: rs[n] = sum_m adj[n][m].
// ---------------------------------------------------------------------------
__global__ __launch_bounds__(256) void k_rs(const float* __restrict__ adj,
                                            float* __restrict__ rs) {
    int row = blockIdx.x;
    float s = 0.f;
    for (int m = threadIdx.x; m < N_; m += 256) s += adj[row * N_ + m];
#pragma unroll
    for (int off = 32; off; off >>= 1) s += __shfl_down(s, off);
    __shared__ float red[4];
    if ((threadIdx.x & 63) == 0) red[threadIdx.x >> 6] = s;
    __syncthreads();
    if (threadIdx.x == 0) rs[row] = red[0] + red[1] + red[2] + red[3];
}

// ---------------------------------------------------------------------------
// k_ax: ax[bt][n] = sum_m x[bt][m] * adj[n][m]   (NT SGEMM)
// ---------------------------------------------------------------------------
__global__ __launch_bounds__(256) void k_ax(const float* __restrict__ x,
                                            const float* __restrict__ adj,
                                            float* __restrict__ ax) {
    __shared__ float As[32][68];
    __shared__ float Bs[32][68];
    int bx = blockIdx.x;
    int by = blockIdx.y;
    int tid = threadIdx.x;
    int tx = tid & 15, ty = tid >> 4;
    int r = tid >> 2;
    int kofs = (tid & 3) * 8;
    const float* xrow = x + (by * 64 + r) * N_;
    const float* arow = adj + (bx * 64 + r) * N_;
    float acc[4][4];
#pragma unroll
    for (int i = 0; i < 4; ++i)
#pragma unroll
        for (int j = 0; j < 4; ++j) acc[i][j] = 0.f;

    for (int k0 = 0; k0 < N_; k0 += 32) {
        float4 a0 = *(const float4*)(xrow + k0 + kofs);
        float4 a1 = *(const float4*)(xrow + k0 + kofs + 4);
        float4 b0 = *(const float4*)(arow + k0 + kofs);
        float4 b1 = *(const float4*)(arow + k0 + kofs + 4);
        __syncthreads();
        As[kofs + 0][r] = a0.x; As[kofs + 1][r] = a0.y;
        As[kofs + 2][r] = a0.z; As[kofs + 3][r] = a0.w;
        As[kofs + 4][r] = a1.x; As[kofs + 5][r] = a1.y;
        As[kofs + 6][r] = a1.z; As[kofs + 7][r] = a1.w;
        Bs[kofs + 0][r] = b0.x; Bs[kofs + 1][r] = b0.y;
        Bs[kofs + 2][r] = b0.z; Bs[kofs + 3][r] = b0.w;
        Bs[kofs + 4][r] = b1.x; Bs[kofs + 5][r] = b1.y;
        Bs[kofs + 6][r] = b1.z; Bs[kofs + 7][r] = b1.w;
        __syncthreads();
#pragma unroll
        for (int kk = 0; kk < 32; ++kk) {
            float4 av = *(const float4*)&As[kk][ty * 4];
            float4 bv = *(const float4*)&Bs[kk][tx * 4];
            float a[4] = {av.x, av.y, av.z, av.w};
            float b[4] = {bv.x, bv.y, bv.z, bv.w};
#pragma unroll
            for (int i = 0; i < 4; ++i)
#pragma unroll
                for (int j = 0; j < 4; ++j) acc[i][j] += a[i] * b[j];
        }
    }
    int obase = (by * 64 + ty * 4) * N_ + bx * 64 + tx * 4;
#pragma unroll
    for (int i = 0; i < 4; ++i) {
        float4 v = make_float4(acc[i][0], acc[i][1], acc[i][2], acc[i][3]);
        *(float4*)(ax + obase + i * N_) = v;
    }
}

// ---------------------------------------------------------------------------
// k_gn: per (bt, group) mean & rsqrt(var+eps)
// ---------------------------------------------------------------------------
__global__ __launch_bounds__(256) void k_gn(const float* __restrict__ x,
                                            const float* __restrict__ ax,
                                            const float* __restrict__ W1n,
                                            const float* __restrict__ B1n,
                                            const float* __restrict__ rs,
                                            const float* __restrict__ w_in,
                                            const float* __restrict__ b_in,
                                            float* __restrict__ mu,
                                            float* __restrict__ rsig) {
    int bt = blockIdx.x;
    int tid = threadIdx.x;
    __shared__ float winv[64], binv[64];
    if (tid < 64) { winv[tid] = w_in[tid]; binv[tid] = b_in[tid]; }
    __syncthreads();
    float s[4] = {0.f, 0.f, 0.f, 0.f};
    float q[4] = {0.f, 0.f, 0.f, 0.f};
    for (int n = tid; n < N_; n += 256) {
        float axn = ax[bt * N_ + n];
        float xn = x[bt * N_ + n];
        float rsn = rs[n];
        const float4* pW = (const float4*)(W1n + n * 64);
        const float4* pB = (const float4*)(B1n + n * 64);
#pragma unroll
        for (int cc = 0; cc < 16; ++cc) {
            float4 wv = pW[cc];
            float4 bv = pB[cc];
            int g = cc >> 2;
            int c0 = cc * 4;
            float v0 = axn * wv.x + rsn * bv.x + xn * winv[c0 + 0] + binv[c0 + 0];
            float v1 = axn * wv.y + rsn * bv.y + xn * winv[c0 + 1] + binv[c0 + 1];
            float v2 = axn * wv.z + rsn * bv.z + xn * winv[c0 + 2] + binv[c0 + 2];
            float v3 = axn * wv.w + rsn * bv.w + xn * winv[c0 + 3] + binv[c0 + 3];
            s[g] += v0 + v1 + v2 + v3;
            q[g] += v0 * v0 + v1 * v1 + v2 * v2 + v3 * v3;
        }
    }
#pragma unroll
    for (int g = 0; g < 4; ++g) {
#pragma unroll
        for (int off = 32; off; off >>= 1) {
            s[g] += __shfl_down(s[g], off);
            q[g] += __shfl_down(q[g], off);
        }
    }
    __shared__ float redS[4][4], redQ[4][4];
    int w = tid >> 6, lane = tid & 63;
    if (lane == 0) {
#pragma unroll
        for (int g = 0; g < 4; ++g) { redS[w][g] = s[g]; redQ[w][g] = q[g]; }
    }
    __syncthreads();
    if (tid < 4) {
        float S = 0.f, Q = 0.f;
#pragma unroll
        for (int ww = 0; ww < 4; ++ww) { S += redS[ww][tid]; Q += redQ[ww][tid]; }
        const float inv = 1.f / 16384.f;
        float m = S * inv;
        float v = Q * inv - m * m;
        mu[bt * 4 + tid] = m;
        rsig[bt * 4 + tid] = rsqrtf(v + 1e-5f);
    }
}

// ---------------------------------------------------------------------------
// k_main v2.1: per block handles 2 nodes (n0, n0+1) for one batch b.
// 512 threads = 8 waves: wave w -> (ni = w>>2, wm = w&3).
// GEMM1: hidden[c][h] = relu(sum_t Hs[c][t]*w1[h][t] + b1[h])   (MFMA bf16)
// GEMM2: t2[t][c]     = sum_h w2[t][h]*hidden[c][h]             (MFMA bf16)
// epilogue: z = Hs + t2 + b2 -> silu -> * w_out -> reduce over c -> out
// ---------------------------------------------------------------------------
__global__ __launch_bounds__(512, 4) void k_main(const float* __restrict__ x,
                                                 const float* __restrict__ ax,
                                                 const float* __restrict__ W1n,
                                                 const float* __restrict__ B1n,
                                                 const float* __restrict__ rs,
                                                 const float* __restrict__ mu,
                                                 const float* __restrict__ rsig,
                                                 const float* __restrict__ w_in,
                                                 const float* __restrict__ b_in,
                                                 const float* __restrict__ gn_w,
                                                 const float* __restrict__ gn_b,
                                                 const float* __restrict__ w1,
                                                 const float* __restrict__ b1,
                                                 const float* __restrict__ w2,
                                                 const float* __restrict__ b2,
                                                 const float* __restrict__ w_out,
                                                 const float* __restrict__ b_out,
                                                 float* __restrict__ out) {
    __shared__ ushort W1s[64][104];       // [h][t]
    __shared__ ushort W2s[96][72];        // [t][h]
    __shared__ ushort Hs[2][64][104];     // [ni][c][t] post-GN bf16
    __shared__ ushort Hd[2][64][72];      // [ni][c][h] relu hidden bf16
    __shared__ union UU {
        struct { float mus[384]; float rgs[384]; float axv[2][96]; float xv[2][96]; } b;
        float redp[2][96][4];
    } U;

    const int tid = threadIdx.x;
    const int n0 = blockIdx.x * 2;
    const int b = blockIdx.y;
    const int wave = tid >> 6;
    const int lane = tid & 63;
    const int lq = lane & 15;      // 0..15
    const int g4 = lane >> 4;      // 0..3
    const int ni = wave >> 2;      // 0..1
    const int wm = wave & 3;       // 0..3

    // ---- phase A: stage weights (fp32 -> bf16) + per-block vectors ----
#pragma unroll
    for (int i = 0; i < 6; ++i) {
        int idx = tid + 512 * i;   // 0..3071
        if (idx < 1536) {
            int h = idx / 24, q = idx % 24;
            float4 v = ((const float4*)w1)[idx];
            ushort4 u = make_ushort4(f2bf(v.x), f2bf(v.y), f2bf(v.z), f2bf(v.w));
            *(ushort4*)&W1s[h][q * 4] = u;
        } else {
            int j = idx - 1536;
            int t = j / 16, q = j % 16;
            float4 v = ((const float4*)w2)[j];
            ushort4 u = make_ushort4(f2bf(v.x), f2bf(v.y), f2bf(v.z), f2bf(v.w));
            *(ushort4*)&W2s[t][q * 4] = u;
        }
    }
    for (int i = tid; i < 768; i += 512) {
        if (i < 384) U.b.mus[i] = mu[b * 384 + i];
        else U.b.rgs[i - 384] = rsig[b * 384 + (i - 384)];
    }
    if (tid < 192) {
        int nn = tid / 96, t = tid - nn * 96;
        int bt = b * T_ + t;
        U.b.axv[nn][t] = ax[bt * N_ + n0 + nn];
        U.b.xv[nn][t] = x[bt * N_ + n0 + nn];
    }
    __syncthreads();

    // ---- phase B: Hs[ni][c][t] = bf16(GN(h)) ----
    {
        int c = tid & 63;
        int tg = (tid >> 6) & 3;
        int nn = tid >> 8;
        int n = n0 + nn;
        float wlc = W1n[n * 64 + c];
        float blc = B1n[n * 64 + c];
        float rsn = rs[n];
        float wic = w_in[c], bic = b_in[c];
        float gwc = gn_w[c], gbc = gn_b[c];
        int g = c >> 4;
#pragma unroll
        for (int i = 0; i < 12; ++i) {
            int t = tg * 24 + 2 * i;
            unsigned int pk = 0;
#pragma unroll
            for (int jj = 0; jj < 2; ++jj) {
                int tt = t + jj;
                float hv = U.b.axv[nn][tt] * wlc + rsn * blc + U.b.xv[nn][tt] * wic + bic;
                float val = (hv - U.b.mus[tt * 4 + g]) * U.b.rgs[tt * 4 + g] * gwc + gbc;
                pk |= ((unsigned int)f2bf(val)) << (16 * jj);
            }
            *(unsigned int*)&Hs[nn][c][t] = pk;
        }
    }
    __syncthreads();

    // ---- phase C: GEMM1 (c x h, K=t=96), relu+bias -> Hd ----
    {
        f32x4 acc1[4] = {{0.f, 0.f, 0.f, 0.f}, {0.f, 0.f, 0.f, 0.f},
                         {0.f, 0.f, 0.f, 0.f}, {0.f, 0.f, 0.f, 0.f}};
#pragma unroll
        for (int k0 = 0; k0 < 96; k0 += 32) {
            short8v a = *(const short8v*)&Hs[ni][16 * wm + lq][k0 + 8 * g4];
#pragma unroll
            for (int nt = 0; nt < 4; ++nt) {
                short8v bb = *(const short8v*)&W1s[16 * nt + lq][k0 + 8 * g4];
                acc1[nt] = __builtin_amdgcn_mfma_f32_16x16x32_bf16(a, bb, acc1[nt], 0, 0, 0);
            }
        }
#pragma unroll
        for (int nt = 0; nt < 4; ++nt) {
            float b1v = b1[16 * nt + lq];
#pragma unroll
            for (int r = 0; r < 4; ++r) {
                int c = 16 * wm + 4 * g4 + r;
                float hvv = fmaxf(acc1[nt][r] + b1v, 0.f);
                Hd[ni][c][16 * nt + lq] = f2bf(hvv);
            }
        }
    }
    // Hd rows [16wm,16wm+16) written & read by the same wave: no barrier needed.

    // ---- phase D: GEMM2 (t x c, K=h=64) + epilogue ----
    {
        f32x4 acc2[6] = {{0.f, 0.f, 0.f, 0.f}, {0.f, 0.f, 0.f, 0.f},
                         {0.f, 0.f, 0.f, 0.f}, {0.f, 0.f, 0.f, 0.f},
                         {0.f, 0.f, 0.f, 0.f}, {0.f, 0.f, 0.f, 0.f}};
#pragma unroll
        for (int ks = 0; ks < 2; ++ks) {
            short8v bb = *(const short8v*)&Hd[ni][16 * wm + lq][32 * ks + 8 * g4];
#pragma unroll
            for (int mt = 0; mt < 6; ++mt) {
                short8v aa = *(const short8v*)&W2s[16 * mt + lq][32 * ks + 8 * g4];
                acc2[mt] = __builtin_amdgcn_mfma_f32_16x16x32_bf16(aa, bb, acc2[mt], 0, 0, 0);
            }
        }
        int cw = 16 * wm + lq;
        float wo = w_out[cw];
#pragma unroll
        for (int mt = 0; mt < 6; ++mt) {
#pragma unroll
            for (int r = 0; r < 4; ++r) {
                int t = 16 * mt + 4 * g4 + r;
                float z = bf2f(Hs[ni][cw][t]) + acc2[mt][r] + b2[t];
                float sz = z / (1.f + __expf(-z));
                float p = sz * wo;
                p += __shfl_xor(p, 1);
                p += __shfl_xor(p, 2);
                p += __shfl_xor(p, 4);
                p += __shfl_xor(p, 8);
                if (lq == 0) U.redp[ni][t][wm] = p;
            }
        }
    }
    __syncthreads();

    // ---- final: cross-wave reduce + store ----
    if (tid < 192) {
        int nn = tid / 96, t = tid - nn * 96;
        float y = U.redp[nn][t][0] + U.redp[nn][t][1] + U.redp[nn][t][2] +
                  U.redp[nn][t][3] + b_out[0];
        out[(b * T_ + t) * N_ + n0 + nn] = y;
    }
}

// ---------------------------------------------------------------------------
extern "C" void kernel_launch(void* const* d_in, const int* in_sizes, int n_in,
                              void* d_out, int out_size, void* d_ws, size_t ws_size,
                              hipStream_t stream) {
    const float* x     = (const float*)d_in[0];
    const float* adj   = (const float*)d_in[1];
    const int*   ntype = (const int*)d_in[2];
    const float* w_in  = (const float*)d_in[3];
    const float* b_in  = (const float*)d_in[4];
    const float* wpool = (const float*)d_in[5];
    const float* emb   = (const float*)d_in[6];
    const float* gn_w  = (const float*)d_in[7];
    const float* gn_b  = (const float*)d_in[8];
    const float* w1    = (const float*)d_in[9];
    const float* b1    = (const float*)d_in[10];
    const float* w2    = (const float*)d_in[11];
    const float* b2    = (const float*)d_in[12];
    const float* w_out = (const float*)d_in[13];
    const float* b_out = (const float*)d_in[14];
    float* out = (float*)d_out;
    float* ws = (float*)d_ws;

    float* wp1 = ws;            // 512
    float* wpb = ws + 512;      // 512
    float* rsv = ws + 1024;     // 1024
    float* W1n = ws + 2048;     // 65536
    float* B1n = ws + 67584;    // 65536
    float* axb = ws + 133120;   // 786432
    float* muv = ws + 919552;   // 3072
    float* rgv = ws + 922624;   // 3072

    k_wp<<<dim3(1), dim3(256), 0, stream>>>(wpool, w_in, b_in, wp1, wpb);
    k_w1n<<<dim3(256), dim3(256), 0, stream>>>(wp1, wpb, emb, ntype, W1n, B1n);
    k_rs<<<dim3(1024), dim3(256), 0, stream>>>(adj, rsv);
    k_ax<<<dim3(16, 12), dim3(256), 0, stream>>>(x, adj, axb);
    k_gn<<<dim3(768), dim3(256), 0, stream>>>(x, axb, W1n, B1n, rsv, w_in, b_in, muv, rgv);
    k_main<<<dim3(512, 8), dim3(512), 0, stream>>>(x, axb, W1n, B1n, rsv, muv, rgv,
                                                   w_in, b_in, gn_w, gn_b,
                                                   w1, b1, w2, b2, w_out, b_out, out);
}

// Round 4
// 127.914 us; speedup vs baseline: 3.1831x; 1.6423x over previous
//
#include <hip/hip_runtime.h>
#include <hip/hip_bf16.h>
#include <math.h>

#define B_   8
#define T_   96
#define N_   1024
#define C_   64
#define H_   64
#define BT_  768
#define EMB_ 8

typedef __attribute__((ext_vector_type(8))) short short8v;
typedef __attribute__((ext_vector_type(4))) float f32x4;

__device__ __forceinline__ ushort f2bf(float f) {   // RNE bf16
    unsigned int u = __float_as_uint(f);
    unsigned int r = (u + 0x7fffu + ((u >> 16) & 1u)) >> 16;
    return (ushort)r;
}
__device__ __forceinline__ float bf2f(ushort h) {
    return __uint_as_float(((unsigned int)h) << 16);
}

// ---------------------------------------------------------------------------
// k_setup (merged): block 0 = wp reduce; block 1 = w1->bf16 padded;
// block 2 = w2->bf16 padded; blocks 3..1026 = adj row sums.
// ---------------------------------------------------------------------------
__global__ __launch_bounds__(256) void k_setup(const float* __restrict__ wpool,
                                               const float* __restrict__ w_in,
                                               const float* __restrict__ b_in,
                                               const float* __restrict__ adj,
                                               const float* __restrict__ w1,
                                               const float* __restrict__ w2,
                                               float* __restrict__ wp1,
                                               float* __restrict__ wpb,
                                               float* __restrict__ rs,
                                               ushort* __restrict__ w1bf,
                                               ushort* __restrict__ w2bf) {
    int bid = blockIdx.x;
    int tid = threadIdx.x;
    if (bid == 0) {
        for (int e = tid; e < EMB_ * C_; e += 256) {
            int d = e >> 6, c = e & 63;
            float s1 = 0.f, s2 = 0.f;
            for (int i = 0; i < C_; ++i) {
                float w = wpool[(d * C_ + i) * C_ + c];
                s1 += w_in[i] * w;
                s2 += b_in[i] * w;
            }
            wp1[e] = s1;
            wpb[e] = s2;
        }
    } else if (bid == 1) {
        for (int e = tid; e < 64 * 96; e += 256) {
            int h = e / 96, t = e - h * 96;
            w1bf[h * 104 + t] = f2bf(w1[e]);
        }
        for (int e = tid; e < 64 * 8; e += 256)
            w1bf[(e >> 3) * 104 + 96 + (e & 7)] = 0;
    } else if (bid == 2) {
        for (int e = tid; e < 96 * 64; e += 256) {
            int t = e >> 6, h = e & 63;
            w2bf[t * 72 + h] = f2bf(w2[e]);
        }
        for (int e = tid; e < 96 * 8; e += 256)
            w2bf[(e >> 3) * 72 + 64 + (e & 7)] = 0;
    } else {
        int row = bid - 3;
        float s = 0.f;
        for (int m = tid; m < N_; m += 256) s += adj[row * N_ + m];
#pragma unroll
        for (int off = 32; off; off >>= 1) s += __shfl_down(s, off);
        __shared__ float red[4];
        if ((tid & 63) == 0) red[tid >> 6] = s;
        __syncthreads();
        if (tid == 0) rs[row] = red[0] + red[1] + red[2] + red[3];
    }
}

// ---------------------------------------------------------------------------
// k_w1n: W1n[n][c] = sum_d emb[type[n]][d]*wp1[d][c];  B1n same with wpb.
// ---------------------------------------------------------------------------
__global__ __launch_bounds__(256) void k_w1n(const float* __restrict__ wp1,
                                             const float* __restrict__ wpb,
                                             const float* __restrict__ emb,
                                             const int* __restrict__ ntype,
                                             float* __restrict__ W1n,
                                             float* __restrict__ B1n) {
    int e = blockIdx.x * 256 + threadIdx.x;  // < 65536
    int n = e >> 6;
    int ty = ntype[n];
    float s1 = 0.f, s2 = 0.f;
#pragma unroll
    for (int d = 0; d < EMB_; ++d) {
        float ev = emb[ty * EMB_ + d];
        s1 += ev * wp1[d * C_ + (e & 63)];
        s2 += ev * wpb[d * C_ + (e & 63)];
    }
    W1n[e] = s1;
    B1n[e] = s2;
}

// ---------------------------------------------------------------------------
// k_ax v2 (bf16 MFMA): ax[bt][n] = sum_m x[bt][m]*adj[n][m].
// 32x32 tile per block, K-step 64, XOR-swizzled bf16 LDS staging.
// grid (N/32=32, BT/32=24), 256 threads (4 waves).
// ---------------------------------------------------------------------------
__global__ __launch_bounds__(256, 4) void k_ax(const float* __restrict__ x,
                                               const float* __restrict__ adj,
                                               float* __restrict__ axo) {
    __shared__ ushort Xs[32 * 64];   // [r][64] swizzled in 16B units
    __shared__ ushort As[32 * 64];
    const int tid = threadIdx.x;
    const int wave = tid >> 6, lane = tid & 63;
    const int lq = lane & 15, g4 = lane >> 4;
    const int n0 = blockIdx.x * 32, m0 = blockIdx.y * 32;
    const int mi = wave >> 1, ni = wave & 1;
    const int sr = tid >> 3, sq = tid & 7;          // staging row/unit
    const int sqx = sq ^ (sr & 7);                  // swizzled unit col
    const int ra = 16 * mi + lq, rb = 16 * ni + lq;

    f32x4 acc = {0.f, 0.f, 0.f, 0.f};

    for (int k0 = 0; k0 < N_; k0 += 64) {
        __syncthreads();
        {
            const float* px = x + (m0 + sr) * N_ + k0 + sq * 8;
            float4 xa = *(const float4*)px;
            float4 xb = *(const float4*)(px + 4);
            union { short8v v; __hip_bfloat162 h[4]; } o;
            o.h[0] = __float22bfloat162_rn(make_float2(xa.x, xa.y));
            o.h[1] = __float22bfloat162_rn(make_float2(xa.z, xa.w));
            o.h[2] = __float22bfloat162_rn(make_float2(xb.x, xb.y));
            o.h[3] = __float22bfloat162_rn(make_float2(xb.z, xb.w));
            *(short8v*)&Xs[sr * 64 + sqx * 8] = o.v;

            const float* pa = adj + (n0 + sr) * N_ + k0 + sq * 8;
            float4 aa = *(const float4*)pa;
            float4 ab = *(const float4*)(pa + 4);
            o.h[0] = __float22bfloat162_rn(make_float2(aa.x, aa.y));
            o.h[1] = __float22bfloat162_rn(make_float2(aa.z, aa.w));
            o.h[2] = __float22bfloat162_rn(make_float2(ab.x, ab.y));
            o.h[3] = __float22bfloat162_rn(make_float2(ab.z, ab.w));
            *(short8v*)&As[sr * 64 + sqx * 8] = o.v;
        }
        __syncthreads();
#pragma unroll
        for (int ks = 0; ks < 2; ++ks) {
            short8v a = *(const short8v*)&Xs[ra * 64 + ((4 * ks + g4) ^ (ra & 7)) * 8];
            short8v bb = *(const short8v*)&As[rb * 64 + ((4 * ks + g4) ^ (rb & 7)) * 8];
            acc = __builtin_amdgcn_mfma_f32_16x16x32_bf16(a, bb, acc, 0, 0, 0);
        }
    }
#pragma unroll
    for (int r = 0; r < 4; ++r)
        axo[(m0 + 16 * mi + 4 * g4 + r) * N_ + n0 + 16 * ni + lq] = acc[r];
}

// ---------------------------------------------------------------------------
// k_gn: per (bt, group) mean & rsqrt(var+eps)  (unchanged, verified)
// ---------------------------------------------------------------------------
__global__ __launch_bounds__(256) void k_gn(const float* __restrict__ x,
                                            const float* __restrict__ ax,
                                            const float* __restrict__ W1n,
                                            const float* __restrict__ B1n,
                                            const float* __restrict__ rs,
                                            const float* __restrict__ w_in,
                                            const float* __restrict__ b_in,
                                            float* __restrict__ mu,
                                            float* __restrict__ rsig) {
    int bt = blockIdx.x;
    int tid = threadIdx.x;
    __shared__ float winv[64], binv[64];
    if (tid < 64) { winv[tid] = w_in[tid]; binv[tid] = b_in[tid]; }
    __syncthreads();
    float s[4] = {0.f, 0.f, 0.f, 0.f};
    float q[4] = {0.f, 0.f, 0.f, 0.f};
    for (int n = tid; n < N_; n += 256) {
        float axn = ax[bt * N_ + n];
        float xn = x[bt * N_ + n];
        float rsn = rs[n];
        const float4* pW = (const float4*)(W1n + n * 64);
        const float4* pB = (const float4*)(B1n + n * 64);
#pragma unroll
        for (int cc = 0; cc < 16; ++cc) {
            float4 wv = pW[cc];
            float4 bv = pB[cc];
            int g = cc >> 2;
            int c0 = cc * 4;
            float v0 = axn * wv.x + rsn * bv.x + xn * winv[c0 + 0] + binv[c0 + 0];
            float v1 = axn * wv.y + rsn * bv.y + xn * winv[c0 + 1] + binv[c0 + 1];
            float v2 = axn * wv.z + rsn * bv.z + xn * winv[c0 + 2] + binv[c0 + 2];
            float v3 = axn * wv.w + rsn * bv.w + xn * winv[c0 + 3] + binv[c0 + 3];
            s[g] += v0 + v1 + v2 + v3;
            q[g] += v0 * v0 + v1 * v1 + v2 * v2 + v3 * v3;
        }
    }
#pragma unroll
    for (int g = 0; g < 4; ++g) {
#pragma unroll
        for (int off = 32; off; off >>= 1) {
            s[g] += __shfl_down(s[g], off);
            q[g] += __shfl_down(q[g], off);
        }
    }
    __shared__ float redS[4][4], redQ[4][4];
    int w = tid >> 6, lane = tid & 63;
    if (lane == 0) {
#pragma unroll
        for (int g = 0; g < 4; ++g) { redS[w][g] = s[g]; redQ[w][g] = q[g]; }
    }
    __syncthreads();
    if (tid < 4) {
        float S = 0.f, Q = 0.f;
#pragma unroll
        for (int ww = 0; ww < 4; ++ww) { S += redS[ww][tid]; Q += redQ[ww][tid]; }
        const float inv = 1.f / 16384.f;
        float m = S * inv;
        float v = Q * inv - m * m;
        mu[bt * 4 + tid] = m;
        rsig[bt * 4 + tid] = rsqrtf(v + 1e-5f);
    }
}

// ---------------------------------------------------------------------------
// k_main v3: 2 nodes per block, 512 threads = 8 waves (ni=wave>>2, wm=wave&3).
// Pre-converted bf16 weights staged by plain 16B copies.
// Phase B: ds_write_b128 (thread owns 8 t for one c) -> conflict-free.
// GEMM1: D[c][h] = mfma(Hs[c,:], W1[h,:]);  GEMM2: D[c][t] = mfma(Hd[c,:], W2[t,:])
//   -> c-reduction is 4 reg adds + 2 shfls per t-tile.
// ---------------------------------------------------------------------------
__global__ __launch_bounds__(512, 4) void k_main(const float* __restrict__ x,
                                                 const float* __restrict__ ax,
                                                 const float* __restrict__ W1n,
                                                 const float* __restrict__ B1n,
                                                 const float* __restrict__ rs,
                                                 const float* __restrict__ mu,
                                                 const float* __restrict__ rsig,
                                                 const float* __restrict__ w_in,
                                                 const float* __restrict__ b_in,
                                                 const float* __restrict__ gn_w,
                                                 const float* __restrict__ gn_b,
                                                 const ushort* __restrict__ wbf,
                                                 const float* __restrict__ b1,
                                                 const float* __restrict__ b2,
                                                 const float* __restrict__ w_out,
                                                 const float* __restrict__ b_out,
                                                 float* __restrict__ out) {
    __shared__ ushort WS[13568];        // W1s[64][104] @0 ; W2s[96][72] @6656
    __shared__ ushort Hs[2][64][104];   // [ni][c][t] post-GN bf16
    __shared__ ushort Hd[2][64][72];    // [ni][c][h] relu hidden bf16
    __shared__ union UU {
        struct { float mus[384]; float rgs[384]; float axv[2][96]; float xv[2][96]; } b;
        float redp[2][96][4];
    } U;
    __shared__ float b1s[64], b2s[96], wos[64];

    const int tid = threadIdx.x;
    const int n0 = blockIdx.x * 2;
    const int b = blockIdx.y;
    const int wave = tid >> 6;
    const int lane = tid & 63;
    const int lq = lane & 15;
    const int g4 = lane >> 4;
    const int ni = wave >> 2;
    const int wm = wave & 3;

    // ---- phase A: stage bf16 weights (16B linear copies) + small vectors ----
    {
        const short8v* g = (const short8v*)wbf;
        short8v* l = (short8v*)WS;
#pragma unroll
        for (int u = tid; u < 1696; u += 512) l[u] = g[u];
    }
    if (tid < 384) {
        U.b.mus[tid] = mu[b * 384 + tid];
        U.b.rgs[tid] = rsig[b * 384 + tid];
    } else {
        int i = tid - 384;               // 0..127
        if (i < 96) b2s[i] = b2[i];
        if (i < 64) { b1s[i] = b1[i]; wos[i] = w_out[i]; }
    }
    if (tid < 192) {
        int nn = tid / 96, t = tid - nn * 96;
        int bt = b * T_ + t;
        U.b.axv[nn][t] = ax[bt * N_ + n0 + nn];
        U.b.xv[nn][t] = x[bt * N_ + n0 + nn];
    }
    __syncthreads();

    // ---- phase B: Hs[nn][c][t0..t0+7] = bf16(GN(h)), b128 writes ----
    {
        const int c = tid & 63;
        const int g = c >> 4;
        float wic = w_in[c], bic = b_in[c];
        float gwc = gn_w[c], gbc = gn_b[c];
        float wl0 = W1n[n0 * 64 + c], bl0 = B1n[n0 * 64 + c];
        float wl1 = W1n[(n0 + 1) * 64 + c], bl1 = B1n[(n0 + 1) * 64 + c];
        float base0 = rs[n0] * bl0 + bic;
        float base1 = rs[n0 + 1] * bl1 + bic;
#pragma unroll
        for (int i = 0; i < 3; ++i) {
            int idx = tid + 512 * i;          // 0..1535 ; c invariant = tid&63
            int nn = (idx >= 768) ? 1 : 0;
            int tc = (idx - nn * 768) >> 6;   // 0..11
            int t0v = tc * 8;
            float wlc = nn ? wl1 : wl0;
            float basev = nn ? base1 : base0;
            float vv[8];
#pragma unroll
            for (int j = 0; j < 8; ++j) {
                int tt = t0v + j;
                float hv = U.b.axv[nn][tt] * wlc + U.b.xv[nn][tt] * wic + basev;
                float sc = U.b.rgs[tt * 4 + g] * gwc;
                vv[j] = (hv - U.b.mus[tt * 4 + g]) * sc + gbc;
            }
            union { short8v v; __hip_bfloat162 h[4]; } o;
#pragma unroll
            for (int j2 = 0; j2 < 4; ++j2)
                o.h[j2] = __float22bfloat162_rn(make_float2(vv[2 * j2], vv[2 * j2 + 1]));
            *(short8v*)&Hs[nn][c][t0v] = o.v;
        }
    }
    __syncthreads();

    ushort (*W1s)[104] = (ushort(*)[104])WS;
    ushort (*W2s)[72] = (ushort(*)[72])(WS + 6656);

    // ---- phase C: GEMM1 D[c][h], relu+bias -> Hd (own-wave rows) ----
    {
        f32x4 acc1[4] = {{0.f, 0.f, 0.f, 0.f}, {0.f, 0.f, 0.f, 0.f},
                         {0.f, 0.f, 0.f, 0.f}, {0.f, 0.f, 0.f, 0.f}};
#pragma unroll
        for (int k0 = 0; k0 < 96; k0 += 32) {
            short8v a = *(const short8v*)&Hs[ni][16 * wm + lq][k0 + 8 * g4];
#pragma unroll
            for (int nt = 0; nt < 4; ++nt) {
                short8v bb = *(const short8v*)&W1s[16 * nt + lq][k0 + 8 * g4];
                acc1[nt] = __builtin_amdgcn_mfma_f32_16x16x32_bf16(a, bb, acc1[nt], 0, 0, 0);
            }
        }
#pragma unroll
        for (int nt = 0; nt < 4; ++nt) {
            float b1v = b1s[16 * nt + lq];
#pragma unroll
            for (int r = 0; r < 4; ++r) {
                int c = 16 * wm + 4 * g4 + r;
                Hd[ni][c][16 * nt + lq] = f2bf(fmaxf(acc1[nt][r] + b1v, 0.f));
            }
        }
    }
    // Hd rows [16wm,16wm+16) written & read by same wave: no barrier.

    // ---- phase D: GEMM2 D[c][t] + epilogue (reg c-sum + 2 shfls) ----
    {
        f32x4 acc2[6] = {{0.f, 0.f, 0.f, 0.f}, {0.f, 0.f, 0.f, 0.f},
                         {0.f, 0.f, 0.f, 0.f}, {0.f, 0.f, 0.f, 0.f},
                         {0.f, 0.f, 0.f, 0.f}, {0.f, 0.f, 0.f, 0.f}};
#pragma unroll
        for (int ks = 0; ks < 2; ++ks) {
            short8v a = *(const short8v*)&Hd[ni][16 * wm + lq][32 * ks + 8 * g4];
#pragma unroll
            for (int mt = 0; mt < 6; ++mt) {
                short8v bb = *(const short8v*)&W2s[16 * mt + lq][32 * ks + 8 * g4];
                acc2[mt] = __builtin_amdgcn_mfma_f32_16x16x32_bf16(a, bb, acc2[mt], 0, 0, 0);
            }
        }
        float wo[4];
#pragma unroll
        for (int r = 0; r < 4; ++r) wo[r] = wos[16 * wm + 4 * g4 + r];
#pragma unroll
        for (int mt = 0; mt < 6; ++mt) {
            int tv = 16 * mt + lq;
            float bz = b2s[tv];
            float pm = 0.f;
#pragma unroll
            for (int r = 0; r < 4; ++r) {
                int c = 16 * wm + 4 * g4 + r;
                float z = bf2f(Hs[ni][c][tv]) + acc2[mt][r] + bz;
                float sg = __builtin_amdgcn_rcpf(1.f + __expf(-z));
                pm += z * sg * wo[r];
            }
            pm += __shfl_xor(pm, 16);
            pm += __shfl_xor(pm, 32);
            if (g4 == 0) U.redp[ni][tv][wm] = pm;
        }
    }
    __syncthreads();

    // ---- final: cross-wave reduce + store ----
    if (tid < 192) {
        int nn = tid / 96, t = tid - nn * 96;
        float y = U.redp[nn][t][0] + U.redp[nn][t][1] + U.redp[nn][t][2] +
                  U.redp[nn][t][3] + b_out[0];
        out[(b * T_ + t) * N_ + n0 + nn] = y;
    }
}

// ---------------------------------------------------------------------------
extern "C" void kernel_launch(void* const* d_in, const int* in_sizes, int n_in,
                              void* d_out, int out_size, void* d_ws, size_t ws_size,
                              hipStream_t stream) {
    const float* x     = (const float*)d_in[0];
    const float* adj   = (const float*)d_in[1];
    const int*   ntype = (const int*)d_in[2];
    const float* w_in  = (const float*)d_in[3];
    const float* b_in  = (const float*)d_in[4];
    const float* wpool = (const float*)d_in[5];
    const float* emb   = (const float*)d_in[6];
    const float* gn_w  = (const float*)d_in[7];
    const float* gn_b  = (const float*)d_in[8];
    const float* w1    = (const float*)d_in[9];
    const float* b1    = (const float*)d_in[10];
    const float* w2    = (const float*)d_in[11];
    const float* b2    = (const float*)d_in[12];
    const float* w_out = (const float*)d_in[13];
    const float* b_out = (const float*)d_in[14];
    float* out = (float*)d_out;
    float* ws = (float*)d_ws;

    float* wp1 = ws;            // 512
    float* wpb = ws + 512;      // 512
    float* rsv = ws + 1024;     // 1024
    float* W1n = ws + 2048;     // 65536
    float* B1n = ws + 67584;    // 65536
    float* axb = ws + 133120;   // 786432
    float* muv = ws + 919552;   // 3072
    float* rgv = ws + 922624;   // 3072
    ushort* wbf = (ushort*)(ws + 925696);  // 13568 ushorts (w1bf | w2bf)
    ushort* w1bf = wbf;
    ushort* w2bf = wbf + 6656;

    k_setup<<<dim3(1027), dim3(256), 0, stream>>>(wpool, w_in, b_in, adj, w1, w2,
                                                  wp1, wpb, rsv, w1bf, w2bf);
    k_w1n<<<dim3(256), dim3(256), 0, stream>>>(wp1, wpb, emb, ntype, W1n, B1n);
    k_ax<<<dim3(32, 24), dim3(256), 0, stream>>>(x, adj, axb);
    k_gn<<<dim3(768), dim3(256), 0, stream>>>(x, axb, W1n, B1n, rsv, w_in, b_in, muv, rgv);
    k_main<<<dim3(512, 8), dim3(512), 0, stream>>>(x, axb, W1n, B1n, rsv, muv, rgv,
                                                   w_in, b_in, gn_w, gn_b,
                                                   wbf, b1, b2, w_out, b_out, out);
}

// Round 6
// 93.940 us; speedup vs baseline: 4.3343x; 1.3617x over previous
//
#include <hip/hip_runtime.h>
#include <hip/hip_bf16.h>
#include <math.h>

#define B_   8
#define T_   96
#define N_   1024
#define C_   64
#define H_   64
#define BT_  768
#define EMB_ 8

typedef __attribute__((ext_vector_type(8))) short short8v;
typedef __attribute__((ext_vector_type(4))) float f32x4;

__device__ __forceinline__ ushort f2bf(float f) {   // RNE bf16
    unsigned int u = __float_as_uint(f);
    unsigned int r = (u + 0x7fffu + ((u >> 16) & 1u)) >> 16;
    return (ushort)r;
}
__device__ __forceinline__ float bf2f(ushort h) {
    return __uint_as_float(((unsigned int)h) << 16);
}

// ---------------------------------------------------------------------------
// k_setup: block 0 = wp1/wpb; block 1 = w1 -> MFMA-A-fragment bf16;
// block 2 = w2 -> MFMA-B-fragment bf16; blocks 3..1026 = adj row sums.
// Frag order: wfrag1[((mt*3+k0)*64+lane)*8+j] = bf16(w1[h][t]),
//   h=16mt+(lane&15), t=32k0+8*(lane>>4)+j   (A[m=h][k=t])
// wfrag2[((mt2*2+ks)*64+lane)*8+j] = bf16(w2[t][h]),
//   t=16mt2+(lane&15), h=32ks+8*(lane>>4)+j  (B[k=h][n=t])
// ---------------------------------------------------------------------------
__global__ __launch_bounds__(256) void k_setup(const float* __restrict__ wpool,
                                               const float* __restrict__ w_in,
                                               const float* __restrict__ b_in,
                                               const float* __restrict__ adj,
                                               const float* __restrict__ w1,
                                               const float* __restrict__ w2,
                                               float* __restrict__ wp1,
                                               float* __restrict__ wpb,
                                               float* __restrict__ rs,
                                               ushort* __restrict__ wfrag1,
                                               ushort* __restrict__ wfrag2) {
    int bid = blockIdx.x;
    int tid = threadIdx.x;
    if (bid == 0) {
        for (int e = tid; e < EMB_ * C_; e += 256) {
            int d = e >> 6, c = e & 63;
            float s1 = 0.f, s2 = 0.f;
            for (int i = 0; i < C_; ++i) {
                float w = wpool[(d * C_ + i) * C_ + c];
                s1 += w_in[i] * w;
                s2 += b_in[i] * w;
            }
            wp1[e] = s1;
            wpb[e] = s2;
        }
    } else if (bid == 1) {
        for (int e = tid; e < 6144; e += 256) {
            int j = e & 7, lane = (e >> 3) & 63, frag = e >> 9;
            int mt = frag / 3, k0 = frag - 3 * mt;
            int h = 16 * mt + (lane & 15);
            int t = 32 * k0 + 8 * (lane >> 4) + j;
            wfrag1[e] = f2bf(w1[h * T_ + t]);
        }
    } else if (bid == 2) {
        for (int e = tid; e < 6144; e += 256) {
            int j = e & 7, lane = (e >> 3) & 63, frag = e >> 9;
            int mt2 = frag >> 1, ks = frag & 1;
            int t = 16 * mt2 + (lane & 15);
            int h = 32 * ks + 8 * (lane >> 4) + j;
            wfrag2[e] = f2bf(w2[t * H_ + h]);
        }
    } else {
        int row = bid - 3;
        float s = 0.f;
        for (int m = tid; m < N_; m += 256) s += adj[row * N_ + m];
#pragma unroll
        for (int off = 32; off; off >>= 1) s += __shfl_down(s, off);
        __shared__ float red[4];
        if ((tid & 63) == 0) red[tid >> 6] = s;
        __syncthreads();
        if (tid == 0) rs[row] = red[0] + red[1] + red[2] + red[3];
    }
}

// ---------------------------------------------------------------------------
// k_tab: 1 block. waves 0..2 (ty): WT/BT[3][64] + per-(ty,group) sums TAB[3][4][9]
//   TAB q: {W, B, W^2, B^2, W*wi, W*bi, wi*B, B*bi, W*B} summed over c in group
// wave 3: GG[4][5] = {sum wi, sum bi, sum wi^2, sum bi^2, sum wi*bi} per group
// ---------------------------------------------------------------------------
__global__ __launch_bounds__(256) void k_tab(const float* __restrict__ wp1,
                                             const float* __restrict__ wpb,
                                             const float* __restrict__ emb,
                                             const float* __restrict__ w_in,
                                             const float* __restrict__ b_in,
                                             float* __restrict__ WT,
                                             float* __restrict__ BTb,
                                             float* __restrict__ TAB,
                                             float* __restrict__ GG) {
    int tid = threadIdx.x;
    int wave = tid >> 6, lane = tid & 63;
    int lq = lane & 15, g = lane >> 4;
    if (wave < 3) {
        int ty = wave, c = lane;
        float w = 0.f, bb = 0.f;
#pragma unroll
        for (int d = 0; d < EMB_; ++d) {
            float ev = emb[ty * EMB_ + d];
            w += ev * wp1[d * C_ + c];
            bb += ev * wpb[d * C_ + c];
        }
        WT[ty * C_ + c] = w;
        BTb[ty * C_ + c] = bb;
        float wi = w_in[c], bi = b_in[c];
        float vals[9] = {w, bb, w * w, bb * bb, w * wi, w * bi, wi * bb, bb * bi, w * bb};
#pragma unroll
        for (int q = 0; q < 9; ++q) {
            vals[q] += __shfl_xor(vals[q], 1);
            vals[q] += __shfl_xor(vals[q], 2);
            vals[q] += __shfl_xor(vals[q], 4);
            vals[q] += __shfl_xor(vals[q], 8);
        }
        if (lq == 0) {
#pragma unroll
            for (int q = 0; q < 9; ++q) TAB[(ty * 4 + g) * 9 + q] = vals[q];
        }
    } else {
        int c = lane;
        float wi = w_in[c], bi = b_in[c];
        float v5[5] = {wi, bi, wi * wi, bi * bi, wi * bi};
#pragma unroll
        for (int q = 0; q < 5; ++q) {
            v5[q] += __shfl_xor(v5[q], 1);
            v5[q] += __shfl_xor(v5[q], 2);
            v5[q] += __shfl_xor(v5[q], 4);
            v5[q] += __shfl_xor(v5[q], 8);
        }
        if (lq == 0) {
#pragma unroll
            for (int q = 0; q < 5; ++q) GG[g * 5 + q] = v5[q];
        }
    }
}

// ---------------------------------------------------------------------------
// k_ax (bf16 MFMA): ax[bt][n] = sum_m x[bt][m]*adj[n][m]  (verified r4)
// ---------------------------------------------------------------------------
__global__ __launch_bounds__(256, 4) void k_ax(const float* __restrict__ x,
                                               const float* __restrict__ adj,
                                               float* __restrict__ axo) {
    __shared__ ushort Xs[32 * 64];
    __shared__ ushort As[32 * 64];
    const int tid = threadIdx.x;
    const int wave = tid >> 6, lane = tid & 63;
    const int lq = lane & 15, g4 = lane >> 4;
    const int n0 = blockIdx.x * 32, m0 = blockIdx.y * 32;
    const int mi = wave >> 1, ni = wave & 1;
    const int sr = tid >> 3, sq = tid & 7;
    const int sqx = sq ^ (sr & 7);
    const int ra = 16 * mi + lq, rb = 16 * ni + lq;

    f32x4 acc = {0.f, 0.f, 0.f, 0.f};

    for (int k0 = 0; k0 < N_; k0 += 64) {
        __syncthreads();
        {
            const float* px = x + (m0 + sr) * N_ + k0 + sq * 8;
            float4 xa = *(const float4*)px;
            float4 xb = *(const float4*)(px + 4);
            union { short8v v; __hip_bfloat162 h[4]; } o;
            o.h[0] = __float22bfloat162_rn(make_float2(xa.x, xa.y));
            o.h[1] = __float22bfloat162_rn(make_float2(xa.z, xa.w));
            o.h[2] = __float22bfloat162_rn(make_float2(xb.x, xb.y));
            o.h[3] = __float22bfloat162_rn(make_float2(xb.z, xb.w));
            *(short8v*)&Xs[sr * 64 + sqx * 8] = o.v;

            const float* pa = adj + (n0 + sr) * N_ + k0 + sq * 8;
            float4 aa = *(const float4*)pa;
            float4 ab = *(const float4*)(pa + 4);
            o.h[0] = __float22bfloat162_rn(make_float2(aa.x, aa.y));
            o.h[1] = __float22bfloat162_rn(make_float2(aa.z, aa.w));
            o.h[2] = __float22bfloat162_rn(make_float2(ab.x, ab.y));
            o.h[3] = __float22bfloat162_rn(make_float2(ab.z, ab.w));
            *(short8v*)&As[sr * 64 + sqx * 8] = o.v;
        }
        __syncthreads();
#pragma unroll
        for (int ks = 0; ks < 2; ++ks) {
            short8v a = *(const short8v*)&Xs[ra * 64 + ((4 * ks + g4) ^ (ra & 7)) * 8];
            short8v bb = *(const short8v*)&As[rb * 64 + ((4 * ks + g4) ^ (rb & 7)) * 8];
            acc = __builtin_amdgcn_mfma_f32_16x16x32_bf16(a, bb, acc, 0, 0, 0);
        }
    }
#pragma unroll
    for (int r = 0; r < 4; ++r)
        axo[(m0 + 16 * mi + 4 * g4 + r) * N_ + n0 + 16 * ni + lq] = acc[r];
}

// ---------------------------------------------------------------------------
// k_gn v2: per bt, per-type feature sums -> mu/rsig via TAB/GG contraction.
// ---------------------------------------------------------------------------
__global__ __launch_bounds__(256) void k_gn(const float* __restrict__ x,
                                            const float* __restrict__ ax,
                                            const float* __restrict__ rs,
                                            const int* __restrict__ ntype,
                                            const float* __restrict__ TAB,
                                            const float* __restrict__ GG,
                                            float* __restrict__ muT,
                                            float* __restrict__ rgT) {
    int bt = blockIdx.x;
    int tid = threadIdx.x;
    const float* axr = ax + bt * N_;
    const float* xr = x + bt * N_;
    float S[23];
#pragma unroll
    for (int q = 0; q < 23; ++q) S[q] = 0.f;
#pragma unroll
    for (int i = 0; i < 4; ++i) {
        int n = tid + 256 * i;
        float a = axr[n], xv = xr[n], r = rs[n];
        int ty = ntype[n];
        float e0 = (ty == 0) ? 1.f : 0.f;
        float e1 = (ty == 1) ? 1.f : 0.f;
        float e2 = (ty == 2) ? 1.f : 0.f;
        float a2 = a * a, axp = a * xv, ar = a * r, xrr = xv * r, r2 = r * r;
        S[0] += e0 * a;   S[1] += e1 * a;   S[2] += e2 * a;
        S[3] += e0 * r;   S[4] += e1 * r;   S[5] += e2 * r;
        S[6] += e0 * a2;  S[7] += e1 * a2;  S[8] += e2 * a2;
        S[9] += e0 * r2;  S[10] += e1 * r2; S[11] += e2 * r2;
        S[12] += e0 * axp; S[13] += e1 * axp; S[14] += e2 * axp;
        S[15] += e0 * ar; S[16] += e1 * ar; S[17] += e2 * ar;
        S[18] += e0 * xrr; S[19] += e1 * xrr; S[20] += e2 * xrr;
        S[21] += xv;      S[22] += xv * xv;
    }
#pragma unroll
    for (int q = 0; q < 23; ++q) {
#pragma unroll
        for (int off = 32; off; off >>= 1) S[q] += __shfl_down(S[q], off);
    }
    __shared__ float wred[4][23];
    __shared__ float tot[23];
    int wave = tid >> 6, lane = tid & 63;
    if (lane == 0) {
#pragma unroll
        for (int q = 0; q < 23; ++q) wred[wave][q] = S[q];
    }
    __syncthreads();
    if (tid < 23) tot[tid] = wred[0][tid] + wred[1][tid] + wred[2][tid] + wred[3][tid];
    __syncthreads();
    if (tid < 4) {
        int g = tid;
        float M = 0.f, Q = 0.f;
#pragma unroll
        for (int ty = 0; ty < 3; ++ty) {
            const float* tb = TAB + (ty * 4 + g) * 9;
            float A1v = tot[0 + ty], R1v = tot[3 + ty], A2v = tot[6 + ty];
            float R2v = tot[9 + ty], AXv = tot[12 + ty], ARv = tot[15 + ty];
            float XRv = tot[18 + ty];
            M += tb[0] * A1v + tb[1] * R1v;
            Q += tb[2] * A2v + tb[3] * R2v +
                 2.f * (tb[4] * AXv + tb[5] * A1v + tb[6] * XRv + tb[7] * R1v + tb[8] * ARv);
        }
        float Sx = tot[21], Sx2 = tot[22];
        const float* gg = GG + g * 5;
        M += gg[0] * Sx + 1024.f * gg[1];
        Q += gg[2] * Sx2 + 2.f * gg[4] * Sx + 1024.f * gg[3];
        const float inv = 1.f / 16384.f;
        float m = M * inv;
        float v = Q * inv - m * m;
        int b = bt / T_, t = bt - b * T_;
        muT[(b * 4 + g) * T_ + t] = m;
        rgT[(b * 4 + g) * T_ + t] = rsqrtf(v + 1e-5f);
    }
}

// ---------------------------------------------------------------------------
// k_main v4.1: 256 threads, 1 node per block, grid (1024, 8). Wave wm owns
// c-tile [16wm,16wm+16). Weights in VGPR fragments (from wfrag1/2).
// Phase B computes GEMM1 B-frag in registers; Hs written once (residual only).
// GEMM1: D[h][c] -> Hd[c][h] b64 writes. GEMM2: D[c][t]. Epilogue fused.
// ---------------------------------------------------------------------------
__global__ __launch_bounds__(256, 3) void k_main(const float* __restrict__ x,
                                                 const float* __restrict__ ax,
                                                 const float* __restrict__ rs,
                                                 const int* __restrict__ ntype,
                                                 const float* __restrict__ WT,
                                                 const float* __restrict__ BTb,
                                                 const float* __restrict__ muT,
                                                 const float* __restrict__ rgT,
                                                 const float* __restrict__ w_in,
                                                 const float* __restrict__ b_in,
                                                 const float* __restrict__ gn_w,
                                                 const float* __restrict__ gn_b,
                                                 const ushort* __restrict__ wfrag1,
                                                 const ushort* __restrict__ wfrag2,
                                                 const float* __restrict__ b1,
                                                 const float* __restrict__ b2,
                                                 const float* __restrict__ w_out,
                                                 const float* __restrict__ b_out,
                                                 float* __restrict__ out) {
    __shared__ ushort Hs[64 * 104];
    __shared__ ushort Hd[64 * 104];
    __shared__ float axs[96], xs[96];
    __shared__ float musT[4 * 100], rgsT[4 * 100];
    __shared__ float redp[96][4];

    const int tid = threadIdx.x;
    const int n = blockIdx.x;
    const int b = blockIdx.y;
    const int wm = tid >> 6;
    const int lane = tid & 63;
    const int lq = lane & 15;
    const int g4 = lane >> 4;

    // ---- weight fragments -> VGPRs (24 x global b128, L2-resident) ----
    short8v w1f[4][3], w2f[6][2];
#pragma unroll
    for (int mt = 0; mt < 4; ++mt)
#pragma unroll
        for (int k0 = 0; k0 < 3; ++k0)
            w1f[mt][k0] = *(const short8v*)(wfrag1 + (((mt * 3 + k0) << 6) + lane) * 8);
#pragma unroll
    for (int mt2 = 0; mt2 < 6; ++mt2)
#pragma unroll
        for (int ks = 0; ks < 2; ++ks)
            w2f[mt2][ks] = *(const short8v*)(wfrag2 + (((mt2 * 2 + ks) << 6) + lane) * 8);

    // ---- stage per-(b,n) vectors (FIXED: no &383 aliasing) ----
    if (tid < 192) {
        int t = (tid < 96) ? tid : tid - 96;
        float v = (tid < 96) ? ax[(b * T_ + t) * N_ + n] : x[(b * T_ + t) * N_ + n];
        if (tid < 96) axs[t] = v; else xs[t] = v;
    }
    for (int j = tid; j < 384; j += 256) {
        int g = j / 96, t = j - 96 * g;
        musT[g * 100 + t] = muT[b * 384 + j];
        rgsT[g * 100 + t] = rgT[b * 384 + j];
    }
    __syncthreads();

    // ---- phase B (B-frag in regs) fused with GEMM1 ----
    const int c = 16 * wm + lq;
    const int ty = ntype[n];
    const float rsn = rs[n];
    const float wlc = WT[ty * C_ + c];
    const float blc = BTb[ty * C_ + c];
    const float wic = w_in[c], bic = b_in[c];
    const float gwc = gn_w[c], gbc = gn_b[c];
    const float base = rsn * blc + bic;

    f32x4 acc1[4] = {{0.f, 0.f, 0.f, 0.f}, {0.f, 0.f, 0.f, 0.f},
                     {0.f, 0.f, 0.f, 0.f}, {0.f, 0.f, 0.f, 0.f}};
#pragma unroll
    for (int k0 = 0; k0 < 3; ++k0) {
        int t8 = 32 * k0 + 8 * g4;
        float4 a0 = *(const float4*)&axs[t8];
        float4 a1 = *(const float4*)&axs[t8 + 4];
        float4 x0 = *(const float4*)&xs[t8];
        float4 x1 = *(const float4*)&xs[t8 + 4];
        float4 m0 = *(const float4*)&musT[wm * 100 + t8];
        float4 m1 = *(const float4*)&musT[wm * 100 + t8 + 4];
        float4 r0 = *(const float4*)&rgsT[wm * 100 + t8];
        float4 r1 = *(const float4*)&rgsT[wm * 100 + t8 + 4];
        float vv[8];
        vv[0] = ((a0.x * wlc + x0.x * wic + base) - m0.x) * (r0.x * gwc) + gbc;
        vv[1] = ((a0.y * wlc + x0.y * wic + base) - m0.y) * (r0.y * gwc) + gbc;
        vv[2] = ((a0.z * wlc + x0.z * wic + base) - m0.z) * (r0.z * gwc) + gbc;
        vv[3] = ((a0.w * wlc + x0.w * wic + base) - m0.w) * (r0.w * gwc) + gbc;
        vv[4] = ((a1.x * wlc + x1.x * wic + base) - m1.x) * (r1.x * gwc) + gbc;
        vv[5] = ((a1.y * wlc + x1.y * wic + base) - m1.y) * (r1.y * gwc) + gbc;
        vv[6] = ((a1.z * wlc + x1.z * wic + base) - m1.z) * (r1.z * gwc) + gbc;
        vv[7] = ((a1.w * wlc + x1.w * wic + base) - m1.w) * (r1.w * gwc) + gbc;
        union { short8v v; __hip_bfloat162 h2[4]; } o;
        o.h2[0] = __float22bfloat162_rn(make_float2(vv[0], vv[1]));
        o.h2[1] = __float22bfloat162_rn(make_float2(vv[2], vv[3]));
        o.h2[2] = __float22bfloat162_rn(make_float2(vv[4], vv[5]));
        o.h2[3] = __float22bfloat162_rn(make_float2(vv[6], vv[7]));
        *(short8v*)&Hs[c * 104 + t8] = o.v;   // residual copy
#pragma unroll
        for (int mt = 0; mt < 4; ++mt)
            acc1[mt] = __builtin_amdgcn_mfma_f32_16x16x32_bf16(w1f[mt][k0], o.v, acc1[mt], 0, 0, 0);
    }

    // ---- relu + bias -> Hd[c][h] (b64 writes; same-wave rows) ----
#pragma unroll
    for (int mt = 0; mt < 4; ++mt) {
        float4 b1v = *(const float4*)&b1[16 * mt + 4 * g4];
        __hip_bfloat162 p0 = __float22bfloat162_rn(make_float2(
            fmaxf(acc1[mt][0] + b1v.x, 0.f), fmaxf(acc1[mt][1] + b1v.y, 0.f)));
        __hip_bfloat162 p1 = __float22bfloat162_rn(make_float2(
            fmaxf(acc1[mt][2] + b1v.z, 0.f), fmaxf(acc1[mt][3] + b1v.w, 0.f)));
        union { uint2 u; __hip_bfloat162 h2[2]; } w;
        w.h2[0] = p0; w.h2[1] = p1;
        *(uint2*)&Hd[c * 104 + 16 * mt + 4 * g4] = w.u;
    }

    // ---- GEMM2: D[c][t] = Hd-row x W2frag ----
    f32x4 acc2[6] = {{0.f, 0.f, 0.f, 0.f}, {0.f, 0.f, 0.f, 0.f},
                     {0.f, 0.f, 0.f, 0.f}, {0.f, 0.f, 0.f, 0.f},
                     {0.f, 0.f, 0.f, 0.f}, {0.f, 0.f, 0.f, 0.f}};
#pragma unroll
    for (int ks = 0; ks < 2; ++ks) {
        short8v af = *(const short8v*)&Hd[c * 104 + 32 * ks + 8 * g4];
#pragma unroll
        for (int mt2 = 0; mt2 < 6; ++mt2)
            acc2[mt2] = __builtin_amdgcn_mfma_f32_16x16x32_bf16(af, w2f[mt2][ks], acc2[mt2], 0, 0, 0);
    }

    // ---- epilogue: residual + b2 -> silu -> *w_out -> reduce over c ----
    float4 wo4 = *(const float4*)&w_out[16 * wm + 4 * g4];
#pragma unroll
    for (int mt2 = 0; mt2 < 6; ++mt2) {
        int tv = 16 * mt2 + lq;
        float bz = b2[tv];
        float pm = 0.f;
#pragma unroll
        for (int r = 0; r < 4; ++r) {
            float res = bf2f(Hs[(16 * wm + 4 * g4 + r) * 104 + tv]);
            float z = res + acc2[mt2][r] + bz;
            float sg = __builtin_amdgcn_rcpf(1.f + __expf(-z));
            pm += z * sg * wo4[r];
        }
        pm += __shfl_xor(pm, 16);
        pm += __shfl_xor(pm, 32);
        if (g4 == 0) redp[tv][wm] = pm;
    }
    __syncthreads();

    if (tid < 96) {
        float4 v = *(const float4*)&redp[tid][0];
        out[(b * T_ + tid) * N_ + n] = v.x + v.y + v.z + v.w + b_out[0];
    }
}

// ---------------------------------------------------------------------------
extern "C" void kernel_launch(void* const* d_in, const int* in_sizes, int n_in,
                              void* d_out, int out_size, void* d_ws, size_t ws_size,
                              hipStream_t stream) {
    const float* x     = (const float*)d_in[0];
    const float* adj   = (const float*)d_in[1];
    const int*   ntype = (const int*)d_in[2];
    const float* w_in  = (const float*)d_in[3];
    const float* b_in  = (const float*)d_in[4];
    const float* wpool = (const float*)d_in[5];
    const float* emb   = (const float*)d_in[6];
    const float* gn_w  = (const float*)d_in[7];
    const float* gn_b  = (const float*)d_in[8];
    const float* w1    = (const float*)d_in[9];
    const float* b1    = (const float*)d_in[10];
    const float* w2    = (const float*)d_in[11];
    const float* b2    = (const float*)d_in[12];
    const float* w_out = (const float*)d_in[13];
    const float* b_out = (const float*)d_in[14];
    float* out = (float*)d_out;
    float* ws = (float*)d_ws;

    float* wp1  = ws;             // 512
    float* wpb  = ws + 512;       // 512
    float* rsv  = ws + 1024;      // 1024
    float* WT   = ws + 2048;      // 192
    float* BTb  = ws + 2240;      // 192
    float* TAB  = ws + 2432;      // 108
    float* GG   = ws + 2540;      // 20
    float* muT  = ws + 2560;      // 3072
    float* rgT  = ws + 5632;      // 3072
    ushort* wfrag1 = (ushort*)(ws + 8704);   // 6144 ushorts
    ushort* wfrag2 = (ushort*)(ws + 11776);  // 6144 ushorts
    float* axb  = ws + 14848;     // 786432

    k_setup<<<dim3(1027), dim3(256), 0, stream>>>(wpool, w_in, b_in, adj, w1, w2,
                                                  wp1, wpb, rsv, wfrag1, wfrag2);
    k_tab<<<dim3(1), dim3(256), 0, stream>>>(wp1, wpb, emb, w_in, b_in,
                                             WT, BTb, TAB, GG);
    k_ax<<<dim3(32, 24), dim3(256), 0, stream>>>(x, adj, axb);
    k_gn<<<dim3(768), dim3(256), 0, stream>>>(x, axb, rsv, ntype, TAB, GG, muT, rgT);
    k_main<<<dim3(1024, 8), dim3(256), 0, stream>>>(x, axb, rsv, ntype, WT, BTb,
                                                    muT, rgT, w_in, b_in, gn_w, gn_b,
                                                    wfrag1, wfrag2, b1, b2,
                                                    w_out, b_out, out);
}